// Round 6
// baseline (603.766 us; speedup 1.0000x reference)
//
#include <hip/hip_runtime.h>

#define NEG_INF -1e30f

typedef __attribute__((ext_vector_type(8))) __bf16 bf16x8;
typedef __attribute__((ext_vector_type(4))) float f32x4;

constexpr int Bb = 16, T = 800, D = 512, V = 5000, L = 100;
constexpr int ROWS = Bb * T;        // 12800
constexpr int S = 2 * L + 1;        // 201
constexpr int SP = 208;             // padded S (13*16)
constexpr int VP = 5120;            // V padded to 128
constexpr int NCB = VP / 128;       // 40 col-blocks (GEMM)
constexpr int NRB = ROWS / 128;     // 100 row-blocks

// float -> bf16 bits, round-to-nearest-even
static __device__ __forceinline__ unsigned short f2bf(float x) {
  union { float f; unsigned u; } v; v.f = x;
  unsigned r = (v.u + 0x7FFFu + ((v.u >> 16) & 1u)) >> 16;
  return (unsigned short)r;
}

// wave_shr:1 (0x138): lane i gets lane i-1; lane 0 (no source, bound_ctrl=0)
// falls back to `old` = NEG_INF. Single VALU op on the DP chain.
static __device__ __forceinline__ float dpp_shr1_neginf(float x) {
  return __int_as_float(__builtin_amdgcn_update_dpp(
      __float_as_int(NEG_INF), __float_as_int(x), 0x138, 0xF, 0xF, false));
}

// volatile vector load: cannot be sunk/duplicated/scalarized -> forces the
// compiler to issue the load HERE and keep the result in VGPRs.
static __device__ __forceinline__ f32x4 vload(const float* p) {
  return *(const volatile f32x4*)p;
}

// ---- hs fp32 -> bf16 (row-major [12800][512]) ----
__global__ __launch_bounds__(256) void k_conv_hs(const float* __restrict__ hs,
                                                 unsigned short* __restrict__ A) {
  int i = blockIdx.x * 256 + threadIdx.x;
  float4 f = ((const float4*)hs)[i];
  ushort4 o;
  o.x = f2bf(f.x); o.y = f2bf(f.y); o.z = f2bf(f.z); o.w = f2bf(f.w);
  ((ushort4*)A)[i] = o;
}

// ---- W [512][5000] fp32 -> Wt [5120][512] bf16 (transposed, pad rows zero) ----
__global__ __launch_bounds__(256) void k_transW(const float* __restrict__ W,
                                                unsigned short* __restrict__ Wt) {
  __shared__ float tile[64][65];
  int v0 = blockIdx.x * 64, k0 = blockIdx.y * 64;
  int tl = threadIdx.x & 63, th = threadIdx.x >> 6;
#pragma unroll
  for (int i = 0; i < 16; i++) {
    int k = k0 + th + i * 4;
    int v = v0 + tl;
    tile[th + i * 4][tl] = (v < V) ? W[(size_t)k * V + v] : 0.f;
  }
  __syncthreads();
#pragma unroll
  for (int i = 0; i < 16; i++) {
    int v = v0 + th + i * 4;
    int k = k0 + tl;
    Wt[(size_t)v * D + k] = f2bf(tile[tl][th + i * 4]);
  }
}

// ---- fused 128x128 GEMM + per-row online softmax partials ----
// XOR-swizzled LDS: row r's global k-octet o lives at LDS octet o^(r&7).
// Kills the 16-way bank conflict of the 128B row stride; global_load_lds
// stays contiguous (we permute the GLOBAL source address per lane instead).
__global__ __launch_bounds__(256) void k_gemm_lse(const unsigned short* __restrict__ A,
                                                  const unsigned short* __restrict__ Wt,
                                                  const float* __restrict__ bias,
                                                  float* __restrict__ partM,
                                                  float* __restrict__ partS) {
  __shared__ unsigned short As[128 * 64];   // [row][octet swizzled] 128x64
  __shared__ unsigned short Bs[128 * 64];
  __shared__ float redM[2][128];
  __shared__ float redS[2][128];

  int tid = threadIdx.x;
  int lane = tid & 63, w = tid >> 6;
  int q = lane >> 4, c = lane & 15;
  int mh = w & 1, nh = w >> 1;          // wave's 64x64 quadrant
  int cb = blockIdx.x;
  int row0 = blockIdx.y * 128, n0 = cb * 128;
  int lr = lane >> 3, lc = lane & 7;    // staging: 8 rows x 8 k-octets per instr
  int oc = (lc ^ lr) * 8;               // swizzled global octet for this lane

  f32x4 acc[4][4];
#pragma unroll
  for (int mt = 0; mt < 4; mt++)
#pragma unroll
    for (int nt = 0; nt < 4; nt++) acc[mt][nt] = (f32x4){0.f, 0.f, 0.f, 0.f};

  for (int kk = 0; kk < D; kk += 64) {
#pragma unroll
    for (int j = 0; j < 4; j++) {
      int i = w * 4 + j;
      const unsigned short* ga = A + (size_t)(row0 + i * 8 + lr) * D + kk + oc;
      __builtin_amdgcn_global_load_lds(
          (const __attribute__((address_space(1))) void*)ga,
          (__attribute__((address_space(3))) void*)(As + i * 512), 16, 0, 0);
      const unsigned short* gb = Wt + (size_t)(n0 + i * 8 + lr) * D + kk + oc;
      __builtin_amdgcn_global_load_lds(
          (const __attribute__((address_space(1))) void*)gb,
          (__attribute__((address_space(3))) void*)(Bs + i * 512), 16, 0, 0);
    }
    __syncthreads();
#pragma unroll
    for (int kq = 0; kq < 2; kq++) {
      int o = ((kq * 4 + q) ^ (c & 7)) * 8;   // row&7 == c&7 for all fragment rows
      bf16x8 af[4], bfr[4];
#pragma unroll
      for (int mt = 0; mt < 4; mt++)
        af[mt] = *(const bf16x8*)(As + (mh * 64 + mt * 16 + c) * 64 + o);
#pragma unroll
      for (int nt = 0; nt < 4; nt++)
        bfr[nt] = *(const bf16x8*)(Bs + (nh * 64 + nt * 16 + c) * 64 + o);
#pragma unroll
      for (int mt = 0; mt < 4; mt++)
#pragma unroll
        for (int nt = 0; nt < 4; nt++)
          acc[mt][nt] = __builtin_amdgcn_mfma_f32_16x16x32_bf16(af[mt], bfr[nt], acc[mt][nt], 0, 0, 0);
    }
    __syncthreads();
  }

  int vcb[4]; float bv[4];
#pragma unroll
  for (int nt = 0; nt < 4; nt++) {
    vcb[nt] = n0 + nh * 64 + nt * 16 + c;
    bv[nt] = (vcb[nt] < V) ? bias[vcb[nt]] : 0.f;
  }
#pragma unroll
  for (int mt = 0; mt < 4; mt++) {
#pragma unroll
    for (int r = 0; r < 4; r++) {
      float x[4]; float m = NEG_INF;
#pragma unroll
      for (int nt = 0; nt < 4; nt++) {
        x[nt] = (vcb[nt] < V) ? (acc[mt][nt][r] + bv[nt]) : NEG_INF;
        m = fmaxf(m, x[nt]);
      }
#pragma unroll
      for (int o = 1; o < 16; o <<= 1) m = fmaxf(m, __shfl_xor(m, o));
      float s = 0.f;
#pragma unroll
      for (int nt = 0; nt < 4; nt++) s += __expf(x[nt] - m);
#pragma unroll
      for (int o = 1; o < 16; o <<= 1) s += __shfl_xor(s, o);
      if (c == 0) {
        int rloc = mh * 64 + mt * 16 + q * 4 + r;
        redM[nh][rloc] = m;
        redS[nh][rloc] = s;
      }
    }
  }
  __syncthreads();
  if (tid < 128) {
    float m0 = redM[0][tid], m1 = redM[1][tid];
    float mm = fmaxf(m0, m1);
    float ss = redS[0][tid] * __expf(m0 - mm) + redS[1][tid] * __expf(m1 - mm);
    partM[(size_t)cb * ROWS + row0 + tid] = mm;
    partS[(size_t)cb * ROWS + row0 + tid] = ss;
  }
}

// ---- combine 40 partials -> lse[row] ----
__global__ __launch_bounds__(256) void k_lse(const float* __restrict__ pM,
                                             const float* __restrict__ pS,
                                             float* __restrict__ lse) {
  int row = blockIdx.x * 256 + threadIdx.x;
  float m = pM[row], s = pS[row];
  for (int cb = 1; cb < NCB; cb++) {
    float M2 = pM[(size_t)cb * ROWS + row], S2 = pS[(size_t)cb * ROWS + row];
    float mn = fmaxf(m, M2);
    s = s * __expf(m - mn) + S2 * __expf(M2 - mn);
    m = mn;
  }
  lse[row] = m + __logf(s);
}

// ---- gathered logits at extended labels ----
__global__ __launch_bounds__(64) void k_gather(const unsigned short* __restrict__ A,
                                               const unsigned short* __restrict__ Wt,
                                               const float* __restrict__ bias,
                                               const int* __restrict__ labels,
                                               const float* __restrict__ lse,
                                               float* __restrict__ glog) {
  int lane = threadIdx.x, q = lane >> 4, c = lane & 15;
  int b = blockIdx.z, t0 = blockIdx.y * 16, s0 = blockIdx.x * 16;
  int s = s0 + c;
  int ev = (s < S && (s & 1)) ? labels[b * L + (s >> 1)] : 0;
  const unsigned short* Brow = Wt + (size_t)ev * D;
  const unsigned short* Arow = A + (size_t)(b * T + t0 + c) * D;
  f32x4 acc = {0.f, 0.f, 0.f, 0.f};
#pragma unroll
  for (int kk = 0; kk < D; kk += 32) {
    bf16x8 a = *(const bf16x8*)(Arow + kk + q * 8);
    bf16x8 bb = *(const bf16x8*)(Brow + kk + q * 8);
    acc = __builtin_amdgcn_mfma_f32_16x16x32_bf16(a, bb, acc, 0, 0, 0);
  }
  float bs = bias[ev];
#pragma unroll
  for (int r = 0; r < 4; r++) {
    int row = b * T + t0 + q * 4 + r;
    glog[(size_t)row * SP + s0 + c] = acc[r] + bs - lse[row];
  }
}

// ---- CTC forward DP: log domain, one wave per utterance, DPP neighbor,
//      VOLATILE register double-buffer prefetch (compiler cannot sink) ----
__global__ __launch_bounds__(64, 1) void k_dp(const float* __restrict__ glog,
                                              const int* __restrict__ labels,
                                              const int* __restrict__ hlens,
                                              const int* __restrict__ llens,
                                              float* __restrict__ tot) {
  int b = blockIdx.x, l = threadIdx.x;
  int col = 4 * l < SP ? 4 * l : SP - 4;   // lanes >=52: clamped, garbage never flows down in s
  const float* rp = glog + (size_t)(b * T) * SP + col;

  // skip gates: state 4l+1 skips from 4l-1 (prev-lane a3); 4l+3 skips from 4l+1
  int i0 = (2 * l < L) ? 2 * l : L - 1;
  int i1 = (2 * l + 1 < L) ? 2 * l + 1 : L - 1;
  int im = (l >= 1) ? 2 * l - 1 : 0; im = im < L ? im : L - 1;
  int lab0 = labels[b * L + i0];
  int lab1 = labels[b * L + i1];
  int labm = labels[b * L + im];
  bool sk1 = (l >= 1) && (lab0 != 0) && (lab0 != labm);
  bool sk3 = (lab1 != 0) && (lab1 != lab0);
  int hl = hlens[b];

  // init t=0
  f32x4 g0 = vload(rp);
  float a0 = (l == 0) ? g0.x : NEG_INF;
  float a1 = (l == 0) ? g0.y : NEG_INF;
  float a2 = NEG_INF, a3 = NEG_INF;

#define DP_STEP(G) {                                                          \
    float p3 = dpp_shr1_neginf(a3);              /* alpha[4l-1] */            \
    float s1 = sk1 ? p3 : NEG_INF;                                            \
    float m0 = fmaxf(a0, p3);                                                 \
    float n0 = m0 + __logf(__expf(a0 - m0) + __expf(p3 - m0)) + (G).x;        \
    float m1 = fmaxf(fmaxf(a1, a0), s1);                                      \
    float n1 = m1 + __logf(__expf(a1 - m1) + __expf(a0 - m1) + __expf(s1 - m1)) + (G).y; \
    float m2 = fmaxf(a2, a1);                                                 \
    float n2 = m2 + __logf(__expf(a2 - m2) + __expf(a1 - m2)) + (G).z;        \
    float s3 = sk3 ? a1 : NEG_INF;                                            \
    float m3 = fmaxf(fmaxf(a3, a2), s3);                                      \
    float n3 = m3 + __logf(__expf(a3 - m3) + __expf(a2 - m3) + __expf(s3 - m3)) + (G).w; \
    a0 = n0; a1 = n1; a2 = n2; a3 = n3; }

#define LD(t_expr) vload(rp + (size_t)({ int t_ = (t_expr); t_ < T ? t_ : T - 1; }) * SP)

  int nsteps = hl - 1;           // steps t = 1 .. hl-1 (hl >= 400 so full >= 49)
  int full = nsteps >> 3;
  int rem = nsteps & 7;

  f32x4 c0 = LD(1), c1 = LD(2), c2 = LD(3), c3 = LD(4),
        c4 = LD(5), c5 = LD(6), c6 = LD(7), c7 = LD(8);

  for (int ch = 0; ch < full; ch++) {
    int tb = 9 + ch * 8;
    f32x4 n0v = LD(tb + 0), n1v = LD(tb + 1), n2v = LD(tb + 2), n3v = LD(tb + 3),
          n4v = LD(tb + 4), n5v = LD(tb + 5), n6v = LD(tb + 6), n7v = LD(tb + 7);
    DP_STEP(c0) DP_STEP(c1) DP_STEP(c2) DP_STEP(c3)
    DP_STEP(c4) DP_STEP(c5) DP_STEP(c6) DP_STEP(c7)
    c0 = n0v; c1 = n1v; c2 = n2v; c3 = n3v;
    c4 = n4v; c5 = n5v; c6 = n6v; c7 = n7v;
  }
  if (rem > 0) DP_STEP(c0)
  if (rem > 1) DP_STEP(c1)
  if (rem > 2) DP_STEP(c2)
  if (rem > 3) DP_STEP(c3)
  if (rem > 4) DP_STEP(c4)
  if (rem > 5) DP_STEP(c5)
  if (rem > 6) DP_STEP(c6)
#undef DP_STEP
#undef LD

  __shared__ float fin[256];
  fin[4 * l] = a0; fin[4 * l + 1] = a1; fin[4 * l + 2] = a2; fin[4 * l + 3] = a3;
  __syncthreads();
  if (l == 0) {
    int ll = llens[b];
    float aL = fin[2 * ll], aP = fin[2 * ll - 1];
    float m = fmaxf(aL, aP);
    tot[b] = m + __logf(__expf(aL - m) + __expf(aP - m));
  }
}

// ---- mean of -tot -> out[0] ----
__global__ void k_final(const float* __restrict__ tot, float* __restrict__ out) {
  int lane = threadIdx.x;
  float v = (lane < Bb) ? tot[lane] : 0.f;
#pragma unroll
  for (int o = 1; o < 16; o <<= 1) v += __shfl_xor(v, o);
  if (lane == 0) out[0] = -v / (float)Bb;
}

extern "C" void kernel_launch(void* const* d_in, const int* in_sizes, int n_in,
                              void* d_out, int out_size, void* d_ws, size_t ws_size,
                              hipStream_t stream) {
  const float* hs    = (const float*)d_in[0];
  const float* W     = (const float*)d_in[1];
  const float* bias  = (const float*)d_in[2];
  const int* hlens   = (const int*)d_in[3];
  const int* labels  = (const int*)d_in[4];
  const int* llens   = (const int*)d_in[5];
  float* out = (float*)d_out;

  char* ws = (char*)d_ws;
  unsigned short* A    = (unsigned short*)(ws);              // 12800*512*2 = 13,107,200
  unsigned short* Wt   = (unsigned short*)(ws + 13107200);   // 5120*512*2  =  5,242,880
  float*          partM= (float*)(ws + 18350080);            // 40*12800*4  =  2,048,000
  float*          partS= (float*)(ws + 20398080);            // 40*12800*4  =  2,048,000
  float*          lse  = (float*)(ws + 22446080);            // 12800*4     =     51,200
  float*          glog = (float*)(ws + 22497280);            // 12800*208*4 = 10,649,600
  float*          tot  = (float*)(ws + 33146880);            // 16*4

  k_conv_hs<<<ROWS * D / 1024, 256, 0, stream>>>(hs, A);
  k_transW<<<dim3(VP / 64, D / 64), 256, 0, stream>>>(W, Wt);
  k_gemm_lse<<<dim3(NCB, NRB), 256, 0, stream>>>(A, Wt, bias, partM, partS);
  k_lse<<<ROWS / 256, 256, 0, stream>>>(partM, partS, lse);
  k_gather<<<dim3(SP / 16, T / 16, Bb), 64, 0, stream>>>(A, Wt, bias, labels, lse, glog);
  k_dp<<<Bb, 64, 0, stream>>>(glog, labels, hlens, llens, tot);
  k_final<<<1, 64, 0, stream>>>(tot, out);

  (void)in_sizes; (void)n_in; (void)out_size; (void)ws_size;
}

// Round 8
// 449.328 us; speedup vs baseline: 1.3437x; 1.3437x over previous
//
#include <hip/hip_runtime.h>

#define NEG_INF -1e30f

typedef __attribute__((ext_vector_type(8))) __bf16 bf16x8;
typedef __attribute__((ext_vector_type(4))) float f32x4;

constexpr int Bb = 16, T = 800, D = 512, V = 5000, L = 100;
constexpr int ROWS = Bb * T;        // 12800
constexpr int S = 2 * L + 1;        // 201
constexpr int SP = 208;             // padded S (13*16)
constexpr int VP = 5120;            // V padded to 128
constexpr int NCB = VP / 128;       // 40 col-blocks (GEMM)
constexpr int NRB = ROWS / 128;     // 100 row-blocks

// float -> bf16 bits, round-to-nearest-even
static __device__ __forceinline__ unsigned short f2bf(float x) {
  union { float f; unsigned u; } v; v.f = x;
  unsigned r = (v.u + 0x7FFFu + ((v.u >> 16) & 1u)) >> 16;
  return (unsigned short)r;
}

// wave_shr:1 (0x138): lane i gets lane i-1; lane 0 (no source, bound_ctrl=0)
// falls back to `old` = NEG_INF. Single VALU op on the DP chain.
static __device__ __forceinline__ float dpp_shr1_neginf(float x) {
  return __int_as_float(__builtin_amdgcn_update_dpp(
      __float_as_int(NEG_INF), __float_as_int(x), 0x138, 0xF, 0xF, false));
}

// ---- hs fp32 -> bf16 (row-major [12800][512]) ----
__global__ __launch_bounds__(256) void k_conv_hs(const float* __restrict__ hs,
                                                 unsigned short* __restrict__ A) {
  int i = blockIdx.x * 256 + threadIdx.x;
  float4 f = ((const float4*)hs)[i];
  ushort4 o;
  o.x = f2bf(f.x); o.y = f2bf(f.y); o.z = f2bf(f.z); o.w = f2bf(f.w);
  ((ushort4*)A)[i] = o;
}

// ---- W [512][5000] fp32 -> Wt [5120][512] bf16 (transposed, pad rows zero) ----
__global__ __launch_bounds__(256) void k_transW(const float* __restrict__ W,
                                                unsigned short* __restrict__ Wt) {
  __shared__ float tile[64][65];
  int v0 = blockIdx.x * 64, k0 = blockIdx.y * 64;
  int tl = threadIdx.x & 63, th = threadIdx.x >> 6;
#pragma unroll
  for (int i = 0; i < 16; i++) {
    int k = k0 + th + i * 4;
    int v = v0 + tl;
    tile[th + i * 4][tl] = (v < V) ? W[(size_t)k * V + v] : 0.f;
  }
  __syncthreads();
#pragma unroll
  for (int i = 0; i < 16; i++) {
    int v = v0 + th + i * 4;
    int k = k0 + tl;
    Wt[(size_t)v * D + k] = f2bf(tile[tl][th + i * 4]);
  }
}

// ---- fused 128x128 GEMM + per-row online softmax partials ----
// XOR-swizzled LDS (row r's k-octet o at LDS octet o^(r&7)): bank-conflict-free.
__global__ __launch_bounds__(256) void k_gemm_lse(const unsigned short* __restrict__ A,
                                                  const unsigned short* __restrict__ Wt,
                                                  const float* __restrict__ bias,
                                                  float* __restrict__ partM,
                                                  float* __restrict__ partS) {
  __shared__ unsigned short As[128 * 64];   // [row][octet swizzled] 128x64
  __shared__ unsigned short Bs[128 * 64];
  __shared__ float redM[2][128];
  __shared__ float redS[2][128];

  int tid = threadIdx.x;
  int lane = tid & 63, w = tid >> 6;
  int q = lane >> 4, c = lane & 15;
  int mh = w & 1, nh = w >> 1;          // wave's 64x64 quadrant
  int cb = blockIdx.x;
  int row0 = blockIdx.y * 128, n0 = cb * 128;
  int lr = lane >> 3, lc = lane & 7;    // staging: 8 rows x 8 k-octets per instr
  int oc = (lc ^ lr) * 8;               // swizzled global octet for this lane

  f32x4 acc[4][4];
#pragma unroll
  for (int mt = 0; mt < 4; mt++)
#pragma unroll
    for (int nt = 0; nt < 4; nt++) acc[mt][nt] = (f32x4){0.f, 0.f, 0.f, 0.f};

  for (int kk = 0; kk < D; kk += 64) {
#pragma unroll
    for (int j = 0; j < 4; j++) {
      int i = w * 4 + j;
      const unsigned short* ga = A + (size_t)(row0 + i * 8 + lr) * D + kk + oc;
      __builtin_amdgcn_global_load_lds(
          (const __attribute__((address_space(1))) void*)ga,
          (__attribute__((address_space(3))) void*)(As + i * 512), 16, 0, 0);
      const unsigned short* gb = Wt + (size_t)(n0 + i * 8 + lr) * D + kk + oc;
      __builtin_amdgcn_global_load_lds(
          (const __attribute__((address_space(1))) void*)gb,
          (__attribute__((address_space(3))) void*)(Bs + i * 512), 16, 0, 0);
    }
    __syncthreads();
#pragma unroll
    for (int kq = 0; kq < 2; kq++) {
      int o = ((kq * 4 + q) ^ (c & 7)) * 8;   // row&7 == c&7 for all fragment rows
      bf16x8 af[4], bfr[4];
#pragma unroll
      for (int mt = 0; mt < 4; mt++)
        af[mt] = *(const bf16x8*)(As + (mh * 64 + mt * 16 + c) * 64 + o);
#pragma unroll
      for (int nt = 0; nt < 4; nt++)
        bfr[nt] = *(const bf16x8*)(Bs + (nh * 64 + nt * 16 + c) * 64 + o);
#pragma unroll
      for (int mt = 0; mt < 4; mt++)
#pragma unroll
        for (int nt = 0; nt < 4; nt++)
          acc[mt][nt] = __builtin_amdgcn_mfma_f32_16x16x32_bf16(af[mt], bfr[nt], acc[mt][nt], 0, 0, 0);
    }
    __syncthreads();
  }

  int vcb[4]; float bv[4];
#pragma unroll
  for (int nt = 0; nt < 4; nt++) {
    vcb[nt] = n0 + nh * 64 + nt * 16 + c;
    bv[nt] = (vcb[nt] < V) ? bias[vcb[nt]] : 0.f;
  }
#pragma unroll
  for (int mt = 0; mt < 4; mt++) {
#pragma unroll
    for (int r = 0; r < 4; r++) {
      float x[4]; float m = NEG_INF;
#pragma unroll
      for (int nt = 0; nt < 4; nt++) {
        x[nt] = (vcb[nt] < V) ? (acc[mt][nt][r] + bv[nt]) : NEG_INF;
        m = fmaxf(m, x[nt]);
      }
#pragma unroll
      for (int o = 1; o < 16; o <<= 1) m = fmaxf(m, __shfl_xor(m, o));
      float s = 0.f;
#pragma unroll
      for (int nt = 0; nt < 4; nt++) s += __expf(x[nt] - m);
#pragma unroll
      for (int o = 1; o < 16; o <<= 1) s += __shfl_xor(s, o);
      if (c == 0) {
        int rloc = mh * 64 + mt * 16 + q * 4 + r;
        redM[nh][rloc] = m;
        redS[nh][rloc] = s;
      }
    }
  }
  __syncthreads();
  if (tid < 128) {
    float m0 = redM[0][tid], m1 = redM[1][tid];
    float mm = fmaxf(m0, m1);
    float ss = redS[0][tid] * __expf(m0 - mm) + redS[1][tid] * __expf(m1 - mm);
    partM[(size_t)cb * ROWS + row0 + tid] = mm;
    partS[(size_t)cb * ROWS + row0 + tid] = ss;
  }
}

// ---- combine 40 partials -> lse[row] ----
__global__ __launch_bounds__(256) void k_lse(const float* __restrict__ pM,
                                             const float* __restrict__ pS,
                                             float* __restrict__ lse) {
  int row = blockIdx.x * 256 + threadIdx.x;
  float m = pM[row], s = pS[row];
  for (int cb = 1; cb < NCB; cb++) {
    float M2 = pM[(size_t)cb * ROWS + row], S2 = pS[(size_t)cb * ROWS + row];
    float mn = fmaxf(m, M2);
    s = s * __expf(m - mn) + S2 * __expf(M2 - mn);
    m = mn;
  }
  lse[row] = m + __logf(s);
}

// ---- gathered logits at extended labels ----
__global__ __launch_bounds__(64) void k_gather(const unsigned short* __restrict__ A,
                                               const unsigned short* __restrict__ Wt,
                                               const float* __restrict__ bias,
                                               const int* __restrict__ labels,
                                               const float* __restrict__ lse,
                                               float* __restrict__ glog) {
  int lane = threadIdx.x, q = lane >> 4, c = lane & 15;
  int b = blockIdx.z, t0 = blockIdx.y * 16, s0 = blockIdx.x * 16;
  int s = s0 + c;
  int ev = (s < S && (s & 1)) ? labels[b * L + (s >> 1)] : 0;
  const unsigned short* Brow = Wt + (size_t)ev * D;
  const unsigned short* Arow = A + (size_t)(b * T + t0 + c) * D;
  f32x4 acc = {0.f, 0.f, 0.f, 0.f};
#pragma unroll
  for (int kk = 0; kk < D; kk += 32) {
    bf16x8 a = *(const bf16x8*)(Arow + kk + q * 8);
    bf16x8 bb = *(const bf16x8*)(Brow + kk + q * 8);
    acc = __builtin_amdgcn_mfma_f32_16x16x32_bf16(a, bb, acc, 0, 0, 0);
  }
  float bs = bias[ev];
#pragma unroll
  for (int r = 0; r < 4; r++) {
    int row = b * T + t0 + q * 4 + r;
    glog[(size_t)row * SP + s0 + c] = acc[r] + bs - lse[row];
  }
}

// ---- CTC forward DP: log domain. 256 threads: waves 1-3 stage 64-step glog
//      chunks into double-buffered LDS; wave 0 runs the serial DP chain
//      reading LDS (ds_read latency ~120cyc, compiler-hoistable) instead of
//      sunk global loads (~500cyc). Plain C, no asm. ----
__global__ __launch_bounds__(256, 1) void k_dp(const float* __restrict__ glog,
                                               const int* __restrict__ labels,
                                               const int* __restrict__ hlens,
                                               const int* __restrict__ llens,
                                               float* __restrict__ tot) {
  constexpr int CH = 64;    // time steps per chunk
  constexpr int RW = 212;   // padded LDS row width (floats)
  __shared__ float buf[2][CH][RW];   // ~107 KB
  __shared__ float fin[256];

  int b = blockIdx.x, tid = threadIdx.x;
  int l = tid & 63, w = tid >> 6;
  int hl = hlens[b];                 // block-uniform
  int nsteps = hl - 1;               // steps t = 1..hl-1
  int nchunks = (nsteps + CH - 1) / CH;
  const float* gb = glog + (size_t)(b * T) * SP;

  // DP lane setup (used by wave 0; harmless elsewhere)
  int col = 4 * l < SP ? 4 * l : SP - 4;   // lanes >=52 clamp; garbage flows only upward in s
  int i0 = (2 * l < L) ? 2 * l : L - 1;
  int i1 = (2 * l + 1 < L) ? 2 * l + 1 : L - 1;
  int im = (l >= 1) ? 2 * l - 1 : 0; im = im < L ? im : L - 1;
  int lab0 = labels[b * L + i0];
  int lab1 = labels[b * L + i1];
  int labm = labels[b * L + im];
  bool sk1 = (l >= 1) && (lab0 != 0) && (lab0 != labm);
  bool sk3 = (lab1 != 0) && (lab1 != lab0);

  float4 g0v = *(const float4*)(gb + col);  // row t=0
  float a0 = (l == 0) ? g0v.x : NEG_INF;
  float a1 = (l == 0) ? g0v.y : NEG_INF;
  float a2 = NEG_INF, a3 = NEG_INF;

  // stage chunk 0 (all 256 threads): rows t = 1..64
  for (int idx = tid; idx < CH * 52; idx += 256) {
    int row = idx / 52, j = idx % 52;
    int t = 1 + row; t = t < T ? t : T - 1;
    *(float4*)&buf[0][row][j * 4] = *(const float4*)(gb + (size_t)t * SP + j * 4);
  }
  __syncthreads();

#define DP_STEP(G) {                                                          \
    float p3 = dpp_shr1_neginf(a3);              /* alpha[4l-1] */            \
    float s1 = sk1 ? p3 : NEG_INF;                                            \
    float m0 = fmaxf(a0, p3);                                                 \
    float n0 = m0 + __logf(__expf(a0 - m0) + __expf(p3 - m0)) + (G).x;        \
    float m1 = fmaxf(fmaxf(a1, a0), s1);                                      \
    float n1 = m1 + __logf(__expf(a1 - m1) + __expf(a0 - m1) + __expf(s1 - m1)) + (G).y; \
    float m2 = fmaxf(a2, a1);                                                 \
    float n2 = m2 + __logf(__expf(a2 - m2) + __expf(a1 - m2)) + (G).z;        \
    float s3 = sk3 ? a1 : NEG_INF;                                            \
    float m3 = fmaxf(fmaxf(a3, a2), s3);                                      \
    float n3 = m3 + __logf(__expf(a3 - m3) + __expf(a2 - m3) + __expf(s3 - m3)) + (G).w; \
    a0 = n0; a1 = n1; a2 = n2; a3 = n3; }

  for (int c = 0; c < nchunks; c++) {
    if (w != 0) {
      // waves 1-3: stage chunk c+1 into the other buffer
      if (c + 1 < nchunks) {
        int tb = 1 + (c + 1) * CH;
        float* dst = &buf[(c + 1) & 1][0][0];
        for (int idx = tid - 64; idx < CH * 52; idx += 192) {
          int row = idx / 52, j = idx % 52;
          int t = tb + row; t = t < T ? t : T - 1;
          *(float4*)(dst + row * RW + j * 4) = *(const float4*)(gb + (size_t)t * SP + j * 4);
        }
      }
    } else {
      // wave 0: 64 DP steps from LDS
      const float* bp = &buf[c & 1][0][0];
      int kbase = c * CH;
#pragma unroll 8
      for (int j = 0; j < CH; j++) {
        if (kbase + j < nsteps) {          // wave-uniform predicate
          float4 G = *(const float4*)(bp + j * RW + col);
          DP_STEP(G)
        }
      }
    }
    __syncthreads();
  }
#undef DP_STEP

  if (w == 0) {
    fin[4 * l] = a0; fin[4 * l + 1] = a1; fin[4 * l + 2] = a2; fin[4 * l + 3] = a3;
  }
  __syncthreads();
  if (tid == 0) {
    int ll = llens[b];
    float aL = fin[2 * ll], aP = fin[2 * ll - 1];
    float m = fmaxf(aL, aP);
    tot[b] = m + __logf(__expf(aL - m) + __expf(aP - m));
  }
}

// ---- mean of -tot -> out[0] ----
__global__ void k_final(const float* __restrict__ tot, float* __restrict__ out) {
  int lane = threadIdx.x;
  float v = (lane < Bb) ? tot[lane] : 0.f;
#pragma unroll
  for (int o = 1; o < 16; o <<= 1) v += __shfl_xor(v, o);
  if (lane == 0) out[0] = -v / (float)Bb;
}

extern "C" void kernel_launch(void* const* d_in, const int* in_sizes, int n_in,
                              void* d_out, int out_size, void* d_ws, size_t ws_size,
                              hipStream_t stream) {
  const float* hs    = (const float*)d_in[0];
  const float* W     = (const float*)d_in[1];
  const float* bias  = (const float*)d_in[2];
  const int* hlens   = (const int*)d_in[3];
  const int* labels  = (const int*)d_in[4];
  const int* llens   = (const int*)d_in[5];
  float* out = (float*)d_out;

  char* ws = (char*)d_ws;
  unsigned short* A    = (unsigned short*)(ws);              // 12800*512*2 = 13,107,200
  unsigned short* Wt   = (unsigned short*)(ws + 13107200);   // 5120*512*2  =  5,242,880
  float*          partM= (float*)(ws + 18350080);            // 40*12800*4  =  2,048,000
  float*          partS= (float*)(ws + 20398080);            // 40*12800*4  =  2,048,000
  float*          lse  = (float*)(ws + 22446080);            // 12800*4     =     51,200
  float*          glog = (float*)(ws + 22497280);            // 12800*208*4 = 10,649,600
  float*          tot  = (float*)(ws + 33146880);            // 16*4

  k_conv_hs<<<ROWS * D / 1024, 256, 0, stream>>>(hs, A);
  k_transW<<<dim3(VP / 64, D / 64), 256, 0, stream>>>(W, Wt);
  k_gemm_lse<<<dim3(NCB, NRB), 256, 0, stream>>>(A, Wt, bias, partM, partS);
  k_lse<<<ROWS / 256, 256, 0, stream>>>(partM, partS, lse);
  k_gather<<<dim3(SP / 16, T / 16, Bb), 64, 0, stream>>>(A, Wt, bias, labels, lse, glog);
  k_dp<<<Bb, 256, 0, stream>>>(glog, labels, hlens, llens, tot);
  k_final<<<1, 64, 0, stream>>>(tot, out);

  (void)in_sizes; (void)n_in; (void)out_size; (void)ws_size;
}

// Round 9
// 347.795 us; speedup vs baseline: 1.7360x; 1.2919x over previous
//
#include <hip/hip_runtime.h>

#define NEG_INF -1e30f

typedef __attribute__((ext_vector_type(8))) __bf16 bf16x8;
typedef __attribute__((ext_vector_type(4))) float f32x4;

constexpr int Bb = 16, T = 800, D = 512, V = 5000, L = 100;
constexpr int ROWS = Bb * T;        // 12800
constexpr int S = 2 * L + 1;        // 201
constexpr int SP = 208;             // padded S (13*16)
constexpr int VP = 5120;            // V padded to 128
constexpr int NCB = VP / 128;       // 40 col-blocks (GEMM)
constexpr int NRB = ROWS / 128;     // 100 row-blocks

// float -> bf16 bits, round-to-nearest-even
static __device__ __forceinline__ unsigned short f2bf(float x) {
  union { float f; unsigned u; } v; v.f = x;
  unsigned r = (v.u + 0x7FFFu + ((v.u >> 16) & 1u)) >> 16;
  return (unsigned short)r;
}

// wave_shr:1 (0x138): lane i gets lane i-1; lane 0 (no source, bound_ctrl=0)
// falls back to `old` = NEG_INF.
static __device__ __forceinline__ float dpp_shr1_neginf(float x) {
  return __int_as_float(__builtin_amdgcn_update_dpp(
      __float_as_int(NEG_INF), __float_as_int(x), 0x138, 0xF, 0xF, false));
}

// ---- hs fp32 -> bf16 (row-major [12800][512]) ----
__global__ __launch_bounds__(256) void k_conv_hs(const float* __restrict__ hs,
                                                 unsigned short* __restrict__ A) {
  int i = blockIdx.x * 256 + threadIdx.x;
  float4 f = ((const float4*)hs)[i];
  ushort4 o;
  o.x = f2bf(f.x); o.y = f2bf(f.y); o.z = f2bf(f.z); o.w = f2bf(f.w);
  ((ushort4*)A)[i] = o;
}

// ---- W [512][5000] fp32 -> Wt [5120][512] bf16 (transposed, pad rows zero) ----
__global__ __launch_bounds__(256) void k_transW(const float* __restrict__ W,
                                                unsigned short* __restrict__ Wt) {
  __shared__ float tile[64][65];
  int v0 = blockIdx.x * 64, k0 = blockIdx.y * 64;
  int tl = threadIdx.x & 63, th = threadIdx.x >> 6;
#pragma unroll
  for (int i = 0; i < 16; i++) {
    int k = k0 + th + i * 4;
    int v = v0 + tl;
    tile[th + i * 4][tl] = (v < V) ? W[(size_t)k * V + v] : 0.f;
  }
  __syncthreads();
#pragma unroll
  for (int i = 0; i < 16; i++) {
    int v = v0 + th + i * 4;
    int k = k0 + tl;
    Wt[(size_t)v * D + k] = f2bf(tile[tl][th + i * 4]);
  }
}

// ---- gathered RAW logits at extended labels: glog[b,t,s] = <hs,W[:,ext]> + b[ext] ----
// (log_softmax's -lse folds out of the DP: every step adds exactly one
//  emission, so tot = rawDP - sum_t lse. DP no longer depends on the GEMM.)
__global__ __launch_bounds__(64) void k_gather(const unsigned short* __restrict__ A,
                                               const unsigned short* __restrict__ Wt,
                                               const float* __restrict__ bias,
                                               const int* __restrict__ labels,
                                               float* __restrict__ glog) {
  int lane = threadIdx.x, q = lane >> 4, c = lane & 15;
  int b = blockIdx.z, t0 = blockIdx.y * 16, s0 = blockIdx.x * 16;
  int s = s0 + c;
  int ev = (s < S && (s & 1)) ? labels[b * L + (s >> 1)] : 0;
  const unsigned short* Brow = Wt + (size_t)ev * D;
  const unsigned short* Arow = A + (size_t)(b * T + t0 + c) * D;
  f32x4 acc = {0.f, 0.f, 0.f, 0.f};
#pragma unroll
  for (int kk = 0; kk < D; kk += 32) {
    bf16x8 a = *(const bf16x8*)(Arow + kk + q * 8);
    bf16x8 bb = *(const bf16x8*)(Brow + kk + q * 8);
    acc = __builtin_amdgcn_mfma_f32_16x16x32_bf16(a, bb, acc, 0, 0, 0);
  }
  float bs = bias[ev];
#pragma unroll
  for (int r = 0; r < 4; r++) {
    int row = b * T + t0 + q * 4 + r;
    glog[(size_t)row * SP + s0 + c] = acc[r] + bs;
  }
}

// ---- FUSED: blocks 0..15 = CTC DP on raw logits (16 CUs);
//             blocks 16..4015 = 128x128 GEMM + softmax partials (rest of chip).
//      Independent work, overlapped in one dispatch. ----
__global__ __launch_bounds__(256) void k_fused(const unsigned short* __restrict__ A,
                                               const unsigned short* __restrict__ Wt,
                                               const float* __restrict__ bias,
                                               const float* __restrict__ glog,
                                               const int* __restrict__ labels,
                                               const int* __restrict__ hlens,
                                               const int* __restrict__ llens,
                                               float* __restrict__ partM,
                                               float* __restrict__ partS,
                                               float* __restrict__ rawtot) {
  __shared__ unsigned short As[128 * 64];   // GEMM path only
  __shared__ unsigned short Bs[128 * 64];
  __shared__ float redM[2][128];
  __shared__ float redS[2][128];

  int blk = blockIdx.x;
  if (blk < Bb) {
    // ================= DP path: one wave, log domain, DPP neighbor ========
    if (threadIdx.x >= 64) return;   // waves 1-3 exit (no barriers in this path)
    int b = blk, l = threadIdx.x;
    int col = 4 * l < SP ? 4 * l : SP - 4;  // lanes >=52 clamp; garbage flows only upward in s
    const float* rp = glog + (size_t)(b * T) * SP + col;
    int i0 = (2 * l < L) ? 2 * l : L - 1;
    int i1 = (2 * l + 1 < L) ? 2 * l + 1 : L - 1;
    int im = (l >= 1) ? 2 * l - 1 : 0; im = im < L ? im : L - 1;
    int lab0 = labels[b * L + i0];
    int lab1 = labels[b * L + i1];
    int labm = labels[b * L + im];
    bool sk1 = (l >= 1) && (lab0 != 0) && (lab0 != labm);
    bool sk3 = (lab1 != 0) && (lab1 != lab0);
    int hl = hlens[b];

    f32x4 g0 = *(const f32x4*)rp;
    float a0 = (l == 0) ? g0.x : NEG_INF;
    float a1 = (l == 0) ? g0.y : NEG_INF;
    float a2 = NEG_INF, a3 = NEG_INF;

#define DP_STEP(G) {                                                          \
    float p3 = dpp_shr1_neginf(a3);              /* alpha[4l-1] */            \
    float s1 = sk1 ? p3 : NEG_INF;                                            \
    float m0 = fmaxf(a0, p3);                                                 \
    float n0 = m0 + __logf(__expf(a0 - m0) + __expf(p3 - m0)) + (G).x;        \
    float m1 = fmaxf(fmaxf(a1, a0), s1);                                      \
    float n1 = m1 + __logf(__expf(a1 - m1) + __expf(a0 - m1) + __expf(s1 - m1)) + (G).y; \
    float m2 = fmaxf(a2, a1);                                                 \
    float n2 = m2 + __logf(__expf(a2 - m2) + __expf(a1 - m2)) + (G).z;        \
    float s3 = sk3 ? a1 : NEG_INF;                                            \
    float m3 = fmaxf(fmaxf(a3, a2), s3);                                      \
    float n3 = m3 + __logf(__expf(a3 - m3) + __expf(a2 - m3) + __expf(s3 - m3)) + (G).w; \
    a0 = n0; a1 = n1; a2 = n2; a3 = n3; }

    for (int t = 1; t < hl; t++) {
      f32x4 G = *(const f32x4*)(rp + (size_t)t * SP);
      DP_STEP(G)
    }
#undef DP_STEP

    // extract alpha[2ll], alpha[2ll-1] via shuffles (uniform component select)
    int ll = llens[b];
    int s1i = 2 * ll, s2i = 2 * ll - 1;
    int c1 = s1i & 3, c2 = s2i & 3;
    float cand1 = c1 == 0 ? a0 : c1 == 1 ? a1 : c1 == 2 ? a2 : a3;
    float cand2 = c2 == 0 ? a0 : c2 == 1 ? a1 : c2 == 2 ? a2 : a3;
    float v1 = __shfl(cand1, s1i >> 2);
    float v2 = __shfl(cand2, s2i >> 2);
    if (l == 0) {
      float m = fmaxf(v1, v2);
      rawtot[b] = m + __logf(__expf(v1 - m) + __expf(v2 - m));
    }
    return;
  }

  // ================= GEMM path (XOR-swizzled LDS, bank-conflict-free) =====
  int gblk = blk - Bb;
  int cb = gblk % NCB, rb = gblk / NCB;
  int tid = threadIdx.x;
  int lane = tid & 63, w = tid >> 6;
  int q = lane >> 4, c = lane & 15;
  int mh = w & 1, nh = w >> 1;
  int row0 = rb * 128, n0 = cb * 128;
  int lr = lane >> 3, lc = lane & 7;
  int oc = (lc ^ lr) * 8;

  f32x4 acc[4][4];
#pragma unroll
  for (int mt = 0; mt < 4; mt++)
#pragma unroll
    for (int nt = 0; nt < 4; nt++) acc[mt][nt] = (f32x4){0.f, 0.f, 0.f, 0.f};

  for (int kk = 0; kk < D; kk += 64) {
#pragma unroll
    for (int j = 0; j < 4; j++) {
      int i = w * 4 + j;
      const unsigned short* ga = A + (size_t)(row0 + i * 8 + lr) * D + kk + oc;
      __builtin_amdgcn_global_load_lds(
          (const __attribute__((address_space(1))) void*)ga,
          (__attribute__((address_space(3))) void*)(As + i * 512), 16, 0, 0);
      const unsigned short* gb = Wt + (size_t)(n0 + i * 8 + lr) * D + kk + oc;
      __builtin_amdgcn_global_load_lds(
          (const __attribute__((address_space(1))) void*)gb,
          (__attribute__((address_space(3))) void*)(Bs + i * 512), 16, 0, 0);
    }
    __syncthreads();
#pragma unroll
    for (int kq = 0; kq < 2; kq++) {
      int o = ((kq * 4 + q) ^ (c & 7)) * 8;
      bf16x8 af[4], bfr[4];
#pragma unroll
      for (int mt = 0; mt < 4; mt++)
        af[mt] = *(const bf16x8*)(As + (mh * 64 + mt * 16 + c) * 64 + o);
#pragma unroll
      for (int nt = 0; nt < 4; nt++)
        bfr[nt] = *(const bf16x8*)(Bs + (nh * 64 + nt * 16 + c) * 64 + o);
#pragma unroll
      for (int mt = 0; mt < 4; mt++)
#pragma unroll
        for (int nt = 0; nt < 4; nt++)
          acc[mt][nt] = __builtin_amdgcn_mfma_f32_16x16x32_bf16(af[mt], bfr[nt], acc[mt][nt], 0, 0, 0);
    }
    __syncthreads();
  }

  int vcb[4]; float bv[4];
#pragma unroll
  for (int nt = 0; nt < 4; nt++) {
    vcb[nt] = n0 + nh * 64 + nt * 16 + c;
    bv[nt] = (vcb[nt] < V) ? bias[vcb[nt]] : 0.f;
  }
#pragma unroll
  for (int mt = 0; mt < 4; mt++) {
#pragma unroll
    for (int r = 0; r < 4; r++) {
      float x[4]; float m = NEG_INF;
#pragma unroll
      for (int nt = 0; nt < 4; nt++) {
        x[nt] = (vcb[nt] < V) ? (acc[mt][nt][r] + bv[nt]) : NEG_INF;
        m = fmaxf(m, x[nt]);
      }
#pragma unroll
      for (int o = 1; o < 16; o <<= 1) m = fmaxf(m, __shfl_xor(m, o));
      float s = 0.f;
#pragma unroll
      for (int nt = 0; nt < 4; nt++) s += __expf(x[nt] - m);
#pragma unroll
      for (int o = 1; o < 16; o <<= 1) s += __shfl_xor(s, o);
      if (c == 0) {
        int rloc = mh * 64 + mt * 16 + q * 4 + r;
        redM[nh][rloc] = m;
        redS[nh][rloc] = s;
      }
    }
  }
  __syncthreads();
  if (tid < 128) {
    float m0 = redM[0][tid], m1 = redM[1][tid];
    float mm = fmaxf(m0, m1);
    float ss = redS[0][tid] * __expf(m0 - mm) + redS[1][tid] * __expf(m1 - mm);
    partM[(size_t)cb * ROWS + row0 + tid] = mm;
    partS[(size_t)cb * ROWS + row0 + tid] = ss;
  }
}

// ---- combine 40 partials -> lse[row] ----
__global__ __launch_bounds__(256) void k_lse(const float* __restrict__ pM,
                                             const float* __restrict__ pS,
                                             float* __restrict__ lse) {
  int row = blockIdx.x * 256 + threadIdx.x;
  float m = pM[row], s = pS[row];
  for (int cb = 1; cb < NCB; cb++) {
    float M2 = pM[(size_t)cb * ROWS + row], S2 = pS[(size_t)cb * ROWS + row];
    float mn = fmaxf(m, M2);
    s = s * __expf(m - mn) + S2 * __expf(M2 - mn);
    m = mn;
  }
  lse[row] = m + __logf(s);
}

// ---- final: tot[b] = rawtot[b] - sum_{t<hl} lse[b,t]; out = mean(-tot) ----
__global__ __launch_bounds__(1024) void k_final(const float* __restrict__ lse,
                                                const float* __restrict__ rawtot,
                                                const int* __restrict__ hlens,
                                                float* __restrict__ out) {
  __shared__ float acc[Bb];
  int w = threadIdx.x >> 6, l = threadIdx.x & 63;  // 16 waves, one per b
  int hl = hlens[w];
  float s = 0.f;
  for (int t = l; t < hl; t += 64) s += lse[w * T + t];
#pragma unroll
  for (int o = 1; o < 64; o <<= 1) s += __shfl_xor(s, o);
  if (l == 0) acc[w] = rawtot[w] - s;
  __syncthreads();
  if (threadIdx.x == 0) {
    float m = 0.f;
    for (int i = 0; i < Bb; i++) m += acc[i];
    out[0] = -m / (float)Bb;
  }
}

extern "C" void kernel_launch(void* const* d_in, const int* in_sizes, int n_in,
                              void* d_out, int out_size, void* d_ws, size_t ws_size,
                              hipStream_t stream) {
  const float* hs    = (const float*)d_in[0];
  const float* W     = (const float*)d_in[1];
  const float* bias  = (const float*)d_in[2];
  const int* hlens   = (const int*)d_in[3];
  const int* labels  = (const int*)d_in[4];
  const int* llens   = (const int*)d_in[5];
  float* out = (float*)d_out;

  char* ws = (char*)d_ws;
  unsigned short* A    = (unsigned short*)(ws);              // 12800*512*2 = 13,107,200
  unsigned short* Wt   = (unsigned short*)(ws + 13107200);   // 5120*512*2  =  5,242,880
  float*          partM= (float*)(ws + 18350080);            // 40*12800*4  =  2,048,000
  float*          partS= (float*)(ws + 20398080);            // 40*12800*4  =  2,048,000
  float*          lse  = (float*)(ws + 22446080);            // 12800*4     =     51,200
  float*          glog = (float*)(ws + 22497280);            // 12800*208*4 = 10,649,600
  float*          rawtot=(float*)(ws + 33146880);            // 16*4

  k_conv_hs<<<ROWS * D / 1024, 256, 0, stream>>>(hs, A);
  k_transW<<<dim3(VP / 64, D / 64), 256, 0, stream>>>(W, Wt);
  k_gather<<<dim3(SP / 16, T / 16, Bb), 64, 0, stream>>>(A, Wt, bias, labels, glog);
  k_fused<<<Bb + NCB * NRB, 256, 0, stream>>>(A, Wt, bias, glog, labels, hlens, llens,
                                              partM, partS, rawtot);
  k_lse<<<ROWS / 256, 256, 0, stream>>>(partM, partS, lse);
  k_final<<<1, 1024, 0, stream>>>(lse, rawtot, hlens, out);

  (void)in_sizes; (void)n_in; (void)out_size; (void)ws_size;
}